// Round 4
// baseline (1495.043 us; speedup 1.0000x reference)
//
#include <hip/hip_runtime.h>
#include <hip/hip_bf16.h>

// B=8, N=2048, D=1024, C=1024, H=512 (fp32 in/out)
//  q = LNReLU(sgm@Wq^T+bq); k = LNReLU(velo@Wk^T+bk)
//  S = q k^T; P = softmax(S); v1 = LNReLU(velo@Wv1^T); v2 = LNReLU(sgm@Wv2^T)
//  out = concat(v2, P@v1)
//
// Round 4: ws proven ~176 MiB (round-3 bpr=1). Attention via 4 key-slabs of
// 512 with exp-epilogue QK (P bf16 + atomic row-sums l, reference m_ref from
// a 32-key boot kernel; m_ref cancels in O/l). No S buffer, no softmax pass,
// every GEMM dispatch >= 512 blocks. All GEMM operands pre-split bf16 hi/lo
// staged via global_load_lds(16B) with pre-swizzled global addresses.

#define BB 8
#define NN 2048
#define DD 1024
#define CC_ 1024
#define HH 512
#define RR (BB*NN)   // 16384 rows

typedef unsigned short ush;
typedef short bf16x8 __attribute__((ext_vector_type(8)));
typedef float f32x4  __attribute__((ext_vector_type(4)));

#define MiB (1024L*1024L)

// ---------- helpers ----------
__device__ __forceinline__ ush f2bf_rne(float x) {
    unsigned u = __float_as_uint(x);
    return (ush)((u + 0x7fffu + ((u >> 16) & 1u)) >> 16);
}
__device__ __forceinline__ float bf2f(ush h) {
    return __uint_as_float((unsigned)h << 16);
}
__device__ __forceinline__ float wave_sum(float v) {
    #pragma unroll
    for (int o = 32; o; o >>= 1) v += __shfl_down(v, o);
    return v;
}

// LDS tile [128 rows][32 bf16] = 64 B/row. Swizzle XORs byte bits 4..5 with
// (row>>1)&3 (involution; preserves 16B chunks).
__device__ __forceinline__ int swzb(int row, int kbyte) {
    return ((row << 6) | kbyte) ^ (((row >> 1) & 3) << 4);
}

// async global->LDS, 16B/lane. LDS dest wave-uniform base + lane*16;
// global src per-lane (pre-swizzled so linear LDS holds swizzled layout).
__device__ __forceinline__ void glds16(const void* g, void* l) {
    __builtin_amdgcn_global_load_lds(
        (const __attribute__((address_space(1))) unsigned*)g,
        (__attribute__((address_space(3))) unsigned*)l, 16, 0, 0);
}

// ---------- split-bf16 MFMA GEMM ----------
// C[M,N] = A[M,K] @ B[N,K]^T. Tile 128x128, BK=32, 4 waves -> 64x64 each.
// AM=1: A pre-split hi/lo, 3 passes (ah*bh, ah*bl, al*bh).
// AM=2: A single bf16,    2 passes (a*bh, a*bl).        B always hi/lo.
// EPI=0: store C fp32. EPI=1: p=exp(s-m_ref), store P bf16 + atomicAdd l.
// EPI=2: C += acc (accumulate).
template<int AM, int EPI>
__global__ __launch_bounds__(256, 3)
void gemm3_kernel(const ush* __restrict__ A0, const ush* __restrict__ A1,
                  const ush* __restrict__ B0, const ush* __restrict__ B1,
                  float* __restrict__ C, ush* __restrict__ Pout,
                  float* __restrict__ ml,
                  int K, int lda, int ldb, int ldc,
                  long sAz, long sBz, long sCz, long sPz)
{
    __shared__ alignas(16) ush aHi[128*32];
    __shared__ alignas(16) ush aLo[128*32];
    __shared__ alignas(16) ush bHi[128*32];
    __shared__ alignas(16) ush bLo[128*32];

    const long bz = blockIdx.z;
    const long mbase = (long)blockIdx.y << 7;
    const long nbase = (long)blockIdx.x << 7;
    const int  t    = threadIdx.x;
    const int  wave = t >> 6, lane = t & 63;
    const int  wr = (wave >> 1) << 6;
    const int  wc = (wave & 1)  << 6;
    const int  fr = lane & 15;
    const int  kg = lane >> 4;

    const ush* Ah = A0 + bz * sAz;
    const ush* Bh = B0 + bz * sBz;
    const ush* Bl = B1 + bz * sBz;

    f32x4 acc[4][4] = {};

    for (int k0 = 0; k0 < K; k0 += 32) {
        #pragma unroll
        for (int i = 0; i < 2; ++i) {
            int rl = (wave << 5) + (i << 4) + (lane >> 2);
            int cs = ((lane & 3) ^ ((rl >> 1) & 3)) << 3;
            long goA = (mbase + rl) * (long)lda + k0 + cs;
            long goB = (nbase + rl) * (long)ldb + k0 + cs;
            glds16(Ah + goA, &aHi[(wave << 10) + (i << 9)]);
            if constexpr (AM == 1) {
                const ush* Al_ = A1 + bz * sAz;
                glds16(Al_ + goA, &aLo[(wave << 10) + (i << 9)]);
            }
            glds16(Bh + goB, &bHi[(wave << 10) + (i << 9)]);
            glds16(Bl + goB, &bLo[(wave << 10) + (i << 9)]);
        }
        __syncthreads();

        bf16x8 ah[4], al[4], bh[4], bl[4];
        #pragma unroll
        for (int i = 0; i < 4; ++i) {
            int ra = wr + (i << 4) + fr, rb = wc + (i << 4) + fr;
            ah[i] = *(const bf16x8*)(aHi + (swzb(ra, kg << 4) >> 1));
            if constexpr (AM == 1)
                al[i] = *(const bf16x8*)(aLo + (swzb(ra, kg << 4) >> 1));
            bh[i] = *(const bf16x8*)(bHi + (swzb(rb, kg << 4) >> 1));
            bl[i] = *(const bf16x8*)(bLo + (swzb(rb, kg << 4) >> 1));
        }
        #pragma unroll
        for (int i = 0; i < 4; ++i) {
            #pragma unroll
            for (int j = 0; j < 4; ++j) {
                acc[i][j] = __builtin_amdgcn_mfma_f32_16x16x32_bf16(ah[i], bh[j], acc[i][j], 0, 0, 0);
                acc[i][j] = __builtin_amdgcn_mfma_f32_16x16x32_bf16(ah[i], bl[j], acc[i][j], 0, 0, 0);
                if constexpr (AM == 1)
                    acc[i][j] = __builtin_amdgcn_mfma_f32_16x16x32_bf16(al[i], bh[j], acc[i][j], 0, 0, 0);
            }
        }
        __syncthreads();
    }

    // C/D layout (m89): col = lane&15, row = (lane>>4)*4 + reg
    if constexpr (EPI == 1) {
        ush*   Pb  = Pout + bz * sPz;
        float* mlb = ml + bz * 2048L * 1024;
        #pragma unroll
        for (int i = 0; i < 4; ++i) {
            #pragma unroll
            for (int q = 0; q < 4; ++q) {
                long grow = mbase + wr + (i << 4) + (kg << 2) + q;   // row in batch
                float m = mlb[grow * 1024];
                float rs = 0.f;
                #pragma unroll
                for (int j = 0; j < 4; ++j) {
                    float p = __expf(acc[i][j][q] - m);
                    rs += p;
                    Pb[grow * 512 + nbase + wc + (j << 4) + fr] = f2bf_rne(p);
                }
                rs += __shfl_xor(rs, 1); rs += __shfl_xor(rs, 2);
                rs += __shfl_xor(rs, 4); rs += __shfl_xor(rs, 8);
                if (fr == 0) atomicAdd(&mlb[grow * 1024 + 1], rs);
            }
        }
    } else {
        float* Cb = C + bz * sCz;
        #pragma unroll
        for (int i = 0; i < 4; ++i) {
            #pragma unroll
            for (int q = 0; q < 4; ++q) {
                long grow = mbase + wr + (i << 4) + (kg << 2) + q;
                float* crow = Cb + grow * (long)ldc + nbase + wc + fr;
                #pragma unroll
                for (int j = 0; j < 4; ++j) {
                    if constexpr (EPI == 2) crow[j << 4] = crow[j << 4] + acc[i][j][q];
                    else                    crow[j << 4] = acc[i][j][q];
                }
            }
        }
    }
}

// ---------- bias + LayerNorm + ReLU; optional hi/lo bf16 output ----------
template<int NC, bool HILO>
__global__ void ln_relu_kernel(const float* __restrict__ Y, int ldy,
                               const float* __restrict__ bias,
                               const float* __restrict__ g, const float* __restrict__ beta,
                               float* __restrict__ outf, ush* __restrict__ oh,
                               ush* __restrict__ ol, int ldo)
{
    constexpr int PER = NC / 256;
    long row = blockIdx.x;
    const float* yr = Y + row * (long)ldy;
    int t = threadIdx.x;
    float v[PER]; float s = 0.f, s2 = 0.f;
    #pragma unroll
    for (int i = 0; i < PER; ++i) {
        int c = t + (i << 8);
        float x = yr[c] + bias[c];
        v[i] = x; s += x; s2 += x * x;
    }
    s = wave_sum(s); s2 = wave_sum(s2);
    __shared__ float ra[4], rb[4];
    int w = t >> 6, l = t & 63;
    if (!l) { ra[w] = s; rb[w] = s2; }
    __syncthreads();
    s  = ra[0] + ra[1] + ra[2] + ra[3];
    s2 = rb[0] + rb[1] + rb[2] + rb[3];
    float mu  = s * (1.0f / NC);
    float var = s2 * (1.0f / NC) - mu * mu;
    float inv = rsqrtf(var + 1e-5f);
    #pragma unroll
    for (int i = 0; i < PER; ++i) {
        int c = t + (i << 8);
        float x = (v[i] - mu) * inv * g[c] + beta[c];
        x = fmaxf(x, 0.0f);
        if constexpr (HILO) {
            ush h = f2bf_rne(x);
            ush lo = f2bf_rne(x - __uint_as_float((unsigned)h << 16));
            oh[row * (long)ldo + c] = h;
            ol[row * (long)ldo + c] = lo;
        } else {
            outf[row * (long)ldo + c] = x;
        }
    }
}

// ---------- fp32 -> hi/lo bf16 split (flat) ----------
__global__ void split_kernel(const float* __restrict__ in, ush* __restrict__ h,
                             ush* __restrict__ l, long n)
{
    long i = ((long)blockIdx.x * 256 + threadIdx.x) * 4;
    if (i >= n) return;
    float4 v = *(const float4*)(in + i);
    ushort4 hh, ll;
    hh.x = f2bf_rne(v.x); ll.x = f2bf_rne(v.x - __uint_as_float((unsigned)hh.x << 16));
    hh.y = f2bf_rne(v.y); ll.y = f2bf_rne(v.y - __uint_as_float((unsigned)hh.y << 16));
    hh.z = f2bf_rne(v.z); ll.z = f2bf_rne(v.z - __uint_as_float((unsigned)hh.z << 16));
    hh.w = f2bf_rne(v.w); ll.w = f2bf_rne(v.w - __uint_as_float((unsigned)hh.w << 16));
    *(ushort4*)(h + i) = hh;
    *(ushort4*)(l + i) = ll;
}

// ---------- per-batch transpose [2048,512] -> [512,2048], hi/lo split ----------
__global__ void transpose_split_kernel(const float* __restrict__ in,
                                       ush* __restrict__ oh, ush* __restrict__ ol)
{
    __shared__ float tile[32][33];
    long bz = blockIdx.z;
    const float* I = in + bz * (long)NN * HH;
    ush* OH = oh + bz * (long)HH * NN;
    ush* OL = ol + bz * (long)HH * NN;
    int c0 = blockIdx.x << 5, r0 = blockIdx.y << 5;
    int tx = threadIdx.x & 31, ty = threadIdx.x >> 5;   // 32 x 8
    #pragma unroll
    for (int i = 0; i < 32; i += 8)
        tile[ty + i][tx] = I[(long)(r0 + ty + i) * HH + c0 + tx];
    __syncthreads();
    #pragma unroll
    for (int i = 0; i < 32; i += 8) {
        float x = tile[tx][ty + i];
        ush h = f2bf_rne(x);
        ush lo = f2bf_rne(x - __uint_as_float((unsigned)h << 16));
        long o = (long)(c0 + ty + i) * NN + r0 + tx;
        OH[o] = h; OL[o] = lo;
    }
}

// ---------- boot: m_ref[row] = max_{key<32} q_row . k_key ; l[row] = 0 ----------
// m/l live at out[row*1024 + 0/1] (v2 half of out is written later).
__global__ void boot_kernel(const ush* __restrict__ qh, const ush* __restrict__ ql,
                            const ush* __restrict__ kh, const ush* __restrict__ kl,
                            float* __restrict__ ml)
{
    int wave = threadIdx.x >> 6, lane = threadIdx.x & 63;
    long row = (long)blockIdx.x * 4 + wave;     // 0..16383
    long bz = row >> 11;
    const ush* qhr = qh + row * 1024;
    const ush* qlr = ql + row * 1024;
    int key = lane & 31;
    const ush* khr = kh + (bz * 2048 + key) * 1024;
    const ush* klr = kl + (bz * 2048 + key) * 1024;
    float acc = 0.f;
    for (int d = 0; d < 1024; d += 8) {
        bf16x8 q8h = *(const bf16x8*)(qhr + d);
        bf16x8 q8l = *(const bf16x8*)(qlr + d);
        bf16x8 k8h = *(const bf16x8*)(khr + d);
        bf16x8 k8l = *(const bf16x8*)(klr + d);
        #pragma unroll
        for (int e = 0; e < 8; ++e) {
            float qf = bf2f((ush)q8h[e]) + bf2f((ush)q8l[e]);
            float kf = bf2f((ush)k8h[e]) + bf2f((ush)k8l[e]);
            acc = fmaf(qf, kf, acc);
        }
    }
    #pragma unroll
    for (int o = 16; o; o >>= 1) acc = fmaxf(acc, __shfl_xor(acc, o));
    if (lane == 0) { ml[row * 1024] = acc; ml[row * 1024 + 1] = 0.f; }
}

// ---------- final: out[:, 512:] /= l ----------
__global__ void normalize_kernel(float* __restrict__ o)
{
    long row = blockIdx.x;
    float inv = 1.0f / o[row * 1024 + 1];
    float* r = o + row * 1024 + 512;
    int t = threadIdx.x;
    r[t] *= inv; r[t + 256] *= inv;
}

// ---------- launch ----------
extern "C" void kernel_launch(void* const* d_in, const int* in_sizes, int n_in,
                              void* d_out, int out_size, void* d_ws, size_t ws_size,
                              hipStream_t stream)
{
    const float* sgm   = (const float*)d_in[0];
    const float* velo  = (const float*)d_in[1];
    const float* Wq    = (const float*)d_in[2];
    const float* bq    = (const float*)d_in[3];
    const float* gq    = (const float*)d_in[4];
    const float* betaq = (const float*)d_in[5];
    const float* Wk    = (const float*)d_in[6];
    const float* bk    = (const float*)d_in[7];
    const float* gk    = (const float*)d_in[8];
    const float* betak = (const float*)d_in[9];
    const float* Wv1   = (const float*)d_in[10];
    const float* bv1   = (const float*)d_in[11];
    const float* gv1   = (const float*)d_in[12];
    const float* betav1= (const float*)d_in[13];
    const float* Wv2   = (const float*)d_in[14];
    const float* bv2   = (const float*)d_in[15];
    const float* gv2   = (const float*)d_in[16];
    const float* betav2= (const float*)d_in[17];
    float* out = (float*)d_out;
    char*  wsb = (char*)d_ws;

    if (ws_size < 176 * MiB) return;   // proven >= 176 MiB in round 3

    // ws byte layout:
    // [0..64)    x hi/lo (velo, then sgm) -> later q hi/lo -> later x(sgm) again
    // [64..128)  k hi/lo
    // [128..160) v1t hi/lo
    // [160..176) weight splits (12 MiB), later P slab (16 MiB), later Wv2 again
    ush* xh   = (ush*)wsb;
    ush* xl   = (ush*)(wsb + 32 * MiB);
    ush* kh   = (ush*)(wsb + 64 * MiB);
    ush* kl   = (ush*)(wsb + 96 * MiB);
    ush* v1th = (ush*)(wsb + 128 * MiB);
    ush* v1tl = (ush*)(wsb + 144 * MiB);
    ush* Wqh  = (ush*)(wsb + 160 * MiB);
    ush* Wql  = (ush*)(wsb + 162 * MiB);
    ush* Wkh  = (ush*)(wsb + 164 * MiB);
    ush* Wkl  = (ush*)(wsb + 166 * MiB);
    ush* Wv1h = (ush*)(wsb + 168 * MiB);
    ush* Wv1l = (ush*)(wsb + 169 * MiB);
    ush* P    = (ush*)(wsb + 160 * MiB);
    float* v1f = out + 8388608L;       // out bytes [32..64) MiB

    dim3 blk(256);

    // weight splits (Wv2 split later; its region is P during attention)
    split_kernel<<<1024, blk, 0, stream>>>(Wq,  Wqh,  Wql,  (long)CC_*DD);
    split_kernel<<<1024, blk, 0, stream>>>(Wk,  Wkh,  Wkl,  (long)CC_*DD);
    split_kernel<<<512,  blk, 0, stream>>>(Wv1, Wv1h, Wv1l, (long)HH*DD);

    // --- velo-derived: k, v1 ---
    split_kernel<<<16384, blk, 0, stream>>>(velo, xh, xl, (long)RR*DD);
    gemm3_kernel<1,0><<<dim3(8,128,1), blk, 0, stream>>>(
        xh, xl, Wkh, Wkl, out, nullptr, nullptr, DD, DD, DD, CC_, 0, 0, 0, 0);
    ln_relu_kernel<1024,true><<<RR, blk, 0, stream>>>(out, CC_, bk, gk, betak, nullptr, kh, kl, CC_);
    gemm3_kernel<1,0><<<dim3(4,128,1), blk, 0, stream>>>(
        xh, xl, Wv1h, Wv1l, out, nullptr, nullptr, DD, DD, DD, HH, 0, 0, 0, 0);
    ln_relu_kernel<512,false><<<RR, blk, 0, stream>>>(out, HH, bv1, gv1, betav1, v1f, nullptr, nullptr, HH);
    transpose_split_kernel<<<dim3(16,64,BB), blk, 0, stream>>>(v1f, v1th, v1tl);

    // --- sgm-derived: q (x region reused; q overwrites x after Yq computed) ---
    split_kernel<<<16384, blk, 0, stream>>>(sgm, xh, xl, (long)RR*DD);
    gemm3_kernel<1,0><<<dim3(8,128,1), blk, 0, stream>>>(
        xh, xl, Wqh, Wql, out, nullptr, nullptr, DD, DD, DD, CC_, 0, 0, 0, 0);
    ln_relu_kernel<1024,true><<<RR, blk, 0, stream>>>(out, CC_, bq, gq, betaq, nullptr, xh, xl, CC_);

    // --- attention ---
    boot_kernel<<<4096, blk, 0, stream>>>(xh, xl, kh, kl, out);
    for (int s = 0; s < 4; ++s) {
        gemm3_kernel<1,1><<<dim3(4,16,8), blk, 0, stream>>>(
            xh, xl, kh + (long)s*512*1024, kl + (long)s*512*1024,
            nullptr, P, out, CC_, CC_, CC_, 0,
            2048L*1024, 2048L*1024, 0, 2048L*512);
        if (s == 0)
            gemm3_kernel<2,0><<<dim3(4,16,8), blk, 0, stream>>>(
                P, nullptr, v1th + s*512, v1tl + s*512,
                out + HH, nullptr, nullptr, 512, 512, NN, CC_,
                2048L*512, 512L*2048, 2048L*1024, 0);
        else
            gemm3_kernel<2,2><<<dim3(4,16,8), blk, 0, stream>>>(
                P, nullptr, v1th + s*512, v1tl + s*512,
                out + HH, nullptr, nullptr, 512, 512, NN, CC_,
                2048L*512, 512L*2048, 2048L*1024, 0);
    }
    normalize_kernel<<<RR, blk, 0, stream>>>(out);

    // --- v2 last (out[:, :512] free until now; q and P regions dead) ---
    split_kernel<<<16384, blk, 0, stream>>>(sgm, xh, xl, (long)RR*DD);
    ush* Wv2h = (ush*)(wsb + 160 * MiB);
    ush* Wv2l = (ush*)(wsb + 161 * MiB);
    split_kernel<<<512, blk, 0, stream>>>(Wv2, Wv2h, Wv2l, (long)HH*DD);
    gemm3_kernel<1,0><<<dim3(4,128,1), blk, 0, stream>>>(
        xh, xl, Wv2h, Wv2l, out, nullptr, nullptr, DD, DD, DD, CC_, 0, 0, 0, 0);
    ln_relu_kernel<512,false><<<RR, blk, 0, stream>>>(out, CC_, bv2, gv2, betav2, out, nullptr, nullptr, CC_);
}

// Round 5
// 1324.000 us; speedup vs baseline: 1.1292x; 1.1292x over previous
//
#include <hip/hip_runtime.h>
#include <hip/hip_bf16.h>

// B=8, N=2048, D=1024, C=1024, H=512 (fp32 in/out)
//  q = LNReLU(sgm@Wq^T+bq); k = LNReLU(velo@Wk^T+bk)
//  S = q k^T; P = softmax(S); v1 = LNReLU(velo@Wv1^T); v2 = LNReLU(sgm@Wv2^T)
//  out = concat(v2, P@v1)
//
// Round 5: boot_kernel (595 us, latency-bound) deleted. Slab-0 QK writes raw
// S fp32 into out[:, 0:512] (free until v2); exp_pass computes per-row
// m = max(S_slab0), P = exp(S-m) bf16, l = sum — m_ref for slabs 1-3.
// m,l parked at out[row,0/1] until normalize. All GEMM operands pre-split
// bf16 hi/lo, staged via global_load_lds(16B) w/ pre-swizzled src.

#define BB 8
#define NN 2048
#define DD 1024
#define CC_ 1024
#define HH 512
#define RR (BB*NN)   // 16384 rows

typedef unsigned short ush;
typedef short bf16x8 __attribute__((ext_vector_type(8)));
typedef float f32x4  __attribute__((ext_vector_type(4)));

#define MiB (1024L*1024L)

// ---------- helpers ----------
__device__ __forceinline__ ush f2bf_rne(float x) {
    unsigned u = __float_as_uint(x);
    return (ush)((u + 0x7fffu + ((u >> 16) & 1u)) >> 16);
}
__device__ __forceinline__ float bf2f(ush h) {
    return __uint_as_float((unsigned)h << 16);
}
__device__ __forceinline__ float wave_sum(float v) {
    #pragma unroll
    for (int o = 32; o; o >>= 1) v += __shfl_down(v, o);
    return v;
}
__device__ __forceinline__ float wave_max(float v) {
    #pragma unroll
    for (int o = 32; o; o >>= 1) v = fmaxf(v, __shfl_down(v, o));
    return v;
}

// LDS tile [128 rows][32 bf16] = 64 B/row. Swizzle XORs byte bits 4..5 with
// (row>>1)&3 (involution; preserves 16B chunks).
__device__ __forceinline__ int swzb(int row, int kbyte) {
    return ((row << 6) | kbyte) ^ (((row >> 1) & 3) << 4);
}

// async global->LDS, 16B/lane. LDS dest wave-uniform base + lane*16;
// global src per-lane (pre-swizzled so linear LDS holds swizzled layout).
__device__ __forceinline__ void glds16(const void* g, void* l) {
    __builtin_amdgcn_global_load_lds(
        (const __attribute__((address_space(1))) unsigned*)g,
        (__attribute__((address_space(3))) unsigned*)l, 16, 0, 0);
}

// ---------- split-bf16 MFMA GEMM ----------
// C[M,N] = A[M,K] @ B[N,K]^T. Tile 128x128, BK=32, 4 waves -> 64x64 each.
// AM=1: A pre-split hi/lo, 3 passes (ah*bh, ah*bl, al*bh).
// AM=2: A single bf16,    2 passes (a*bh, a*bl).        B always hi/lo.
// EPI=0: store C fp32. EPI=1: p=exp(s-m), store P bf16 + atomicAdd l.
// EPI=2: C += acc.
template<int AM, int EPI>
__global__ __launch_bounds__(256, 4)
void gemm3_kernel(const ush* __restrict__ A0, const ush* __restrict__ A1,
                  const ush* __restrict__ B0, const ush* __restrict__ B1,
                  float* __restrict__ C, ush* __restrict__ Pout,
                  float* __restrict__ ml,
                  int K, int lda, int ldb, int ldc,
                  long sAz, long sBz, long sCz, long sPz)
{
    __shared__ alignas(16) ush aHi[128*32];
    __shared__ alignas(16) ush aLo[128*32];
    __shared__ alignas(16) ush bHi[128*32];
    __shared__ alignas(16) ush bLo[128*32];

    const long bz = blockIdx.z;
    const long mbase = (long)blockIdx.y << 7;
    const long nbase = (long)blockIdx.x << 7;
    const int  t    = threadIdx.x;
    const int  wave = t >> 6, lane = t & 63;
    const int  wr = (wave >> 1) << 6;
    const int  wc = (wave & 1)  << 6;
    const int  fr = lane & 15;
    const int  kg = lane >> 4;

    const ush* Ah = A0 + bz * sAz;
    const ush* Bh = B0 + bz * sBz;
    const ush* Bl = B1 + bz * sBz;

    f32x4 acc[4][4] = {};

    for (int k0 = 0; k0 < K; k0 += 32) {
        #pragma unroll
        for (int i = 0; i < 2; ++i) {
            int rl = (wave << 5) + (i << 4) + (lane >> 2);
            int cs = ((lane & 3) ^ ((rl >> 1) & 3)) << 3;
            long goA = (mbase + rl) * (long)lda + k0 + cs;
            long goB = (nbase + rl) * (long)ldb + k0 + cs;
            glds16(Ah + goA, &aHi[(wave << 10) + (i << 9)]);
            if constexpr (AM == 1) {
                const ush* Al_ = A1 + bz * sAz;
                glds16(Al_ + goA, &aLo[(wave << 10) + (i << 9)]);
            }
            glds16(Bh + goB, &bHi[(wave << 10) + (i << 9)]);
            glds16(Bl + goB, &bLo[(wave << 10) + (i << 9)]);
        }
        __syncthreads();

        bf16x8 ah[4], al[4], bh[4], bl[4];
        #pragma unroll
        for (int i = 0; i < 4; ++i) {
            int ra = wr + (i << 4) + fr, rb = wc + (i << 4) + fr;
            ah[i] = *(const bf16x8*)(aHi + (swzb(ra, kg << 4) >> 1));
            if constexpr (AM == 1)
                al[i] = *(const bf16x8*)(aLo + (swzb(ra, kg << 4) >> 1));
            bh[i] = *(const bf16x8*)(bHi + (swzb(rb, kg << 4) >> 1));
            bl[i] = *(const bf16x8*)(bLo + (swzb(rb, kg << 4) >> 1));
        }
        #pragma unroll
        for (int i = 0; i < 4; ++i) {
            #pragma unroll
            for (int j = 0; j < 4; ++j) {
                acc[i][j] = __builtin_amdgcn_mfma_f32_16x16x32_bf16(ah[i], bh[j], acc[i][j], 0, 0, 0);
                acc[i][j] = __builtin_amdgcn_mfma_f32_16x16x32_bf16(ah[i], bl[j], acc[i][j], 0, 0, 0);
                if constexpr (AM == 1)
                    acc[i][j] = __builtin_amdgcn_mfma_f32_16x16x32_bf16(al[i], bh[j], acc[i][j], 0, 0, 0);
            }
        }
        __syncthreads();
    }

    // C/D layout (m89): col = lane&15, row = (lane>>4)*4 + reg
    if constexpr (EPI == 1) {
        ush*   Pb  = Pout + bz * sPz;
        float* mlb = ml + bz * 2048L * 1024;
        #pragma unroll
        for (int i = 0; i < 4; ++i) {
            #pragma unroll
            for (int q = 0; q < 4; ++q) {
                long grow = mbase + wr + (i << 4) + (kg << 2) + q;   // row in batch
                float m = mlb[grow * 1024];
                float rs = 0.f;
                #pragma unroll
                for (int j = 0; j < 4; ++j) {
                    float p = __expf(acc[i][j][q] - m);
                    rs += p;
                    Pb[grow * 512 + nbase + wc + (j << 4) + fr] = f2bf_rne(p);
                }
                rs += __shfl_xor(rs, 1); rs += __shfl_xor(rs, 2);
                rs += __shfl_xor(rs, 4); rs += __shfl_xor(rs, 8);
                if (fr == 0) atomicAdd(&mlb[grow * 1024 + 1], rs);
            }
        }
    } else {
        float* Cb = C + bz * sCz;
        #pragma unroll
        for (int i = 0; i < 4; ++i) {
            #pragma unroll
            for (int q = 0; q < 4; ++q) {
                long grow = mbase + wr + (i << 4) + (kg << 2) + q;
                float* crow = Cb + grow * (long)ldc + nbase + wc + fr;
                #pragma unroll
                for (int j = 0; j < 4; ++j) {
                    if constexpr (EPI == 2) crow[j << 4] = crow[j << 4] + acc[i][j][q];
                    else                    crow[j << 4] = acc[i][j][q];
                }
            }
        }
    }
}

// ---------- bias + LayerNorm + ReLU; optional hi/lo bf16 output ----------
template<int NC, bool HILO>
__global__ void ln_relu_kernel(const float* __restrict__ Y, int ldy,
                               const float* __restrict__ bias,
                               const float* __restrict__ g, const float* __restrict__ beta,
                               float* __restrict__ outf, ush* __restrict__ oh,
                               ush* __restrict__ ol, int ldo)
{
    constexpr int PER = NC / 256;
    long row = blockIdx.x;
    const float* yr = Y + row * (long)ldy;
    int t = threadIdx.x;
    float v[PER]; float s = 0.f, s2 = 0.f;
    #pragma unroll
    for (int i = 0; i < PER; ++i) {
        int c = t + (i << 8);
        float x = yr[c] + bias[c];
        v[i] = x; s += x; s2 += x * x;
    }
    s = wave_sum(s); s2 = wave_sum(s2);
    __shared__ float ra[4], rb[4];
    int w = t >> 6, l = t & 63;
    if (!l) { ra[w] = s; rb[w] = s2; }
    __syncthreads();
    s  = ra[0] + ra[1] + ra[2] + ra[3];
    s2 = rb[0] + rb[1] + rb[2] + rb[3];
    float mu  = s * (1.0f / NC);
    float var = s2 * (1.0f / NC) - mu * mu;
    float inv = rsqrtf(var + 1e-5f);
    #pragma unroll
    for (int i = 0; i < PER; ++i) {
        int c = t + (i << 8);
        float x = (v[i] - mu) * inv * g[c] + beta[c];
        x = fmaxf(x, 0.0f);
        if constexpr (HILO) {
            ush h = f2bf_rne(x);
            ush lo = f2bf_rne(x - __uint_as_float((unsigned)h << 16));
            oh[row * (long)ldo + c] = h;
            ol[row * (long)ldo + c] = lo;
        } else {
            outf[row * (long)ldo + c] = x;
        }
    }
}

// ---------- fp32 -> hi/lo bf16 split (flat) ----------
__global__ void split_kernel(const float* __restrict__ in, ush* __restrict__ h,
                             ush* __restrict__ l, long n)
{
    long i = ((long)blockIdx.x * 256 + threadIdx.x) * 4;
    if (i >= n) return;
    float4 v = *(const float4*)(in + i);
    ushort4 hh, ll;
    hh.x = f2bf_rne(v.x); ll.x = f2bf_rne(v.x - __uint_as_float((unsigned)hh.x << 16));
    hh.y = f2bf_rne(v.y); ll.y = f2bf_rne(v.y - __uint_as_float((unsigned)hh.y << 16));
    hh.z = f2bf_rne(v.z); ll.z = f2bf_rne(v.z - __uint_as_float((unsigned)hh.z << 16));
    hh.w = f2bf_rne(v.w); ll.w = f2bf_rne(v.w - __uint_as_float((unsigned)hh.w << 16));
    *(ushort4*)(h + i) = hh;
    *(ushort4*)(l + i) = ll;
}

// ---------- per-batch transpose [2048,512] -> [512,2048], hi/lo split ----------
__global__ void transpose_split_kernel(const float* __restrict__ in,
                                       ush* __restrict__ oh, ush* __restrict__ ol)
{
    __shared__ float tile[32][33];
    long bz = blockIdx.z;
    const float* I = in + bz * (long)NN * HH;
    ush* OH = oh + bz * (long)HH * NN;
    ush* OL = ol + bz * (long)HH * NN;
    int c0 = blockIdx.x << 5, r0 = blockIdx.y << 5;
    int tx = threadIdx.x & 31, ty = threadIdx.x >> 5;   // 32 x 8
    #pragma unroll
    for (int i = 0; i < 32; i += 8)
        tile[ty + i][tx] = I[(long)(r0 + ty + i) * HH + c0 + tx];
    __syncthreads();
    #pragma unroll
    for (int i = 0; i < 32; i += 8) {
        float x = tile[tx][ty + i];
        ush h = f2bf_rne(x);
        ush lo = f2bf_rne(x - __uint_as_float((unsigned)h << 16));
        long o = (long)(c0 + ty + i) * NN + r0 + tx;
        OH[o] = h; OL[o] = lo;
    }
}

// ---------- exp pass over slab-0 scores ----------
// S fp32 at ml[row*1024 + 0..511]; computes m=rowmax, P=exp(S-m) bf16,
// l=rowsum; stores m,l at ml[row*1024 + 0/1] (after S consumed).
__global__ void exp_pass_kernel(float* __restrict__ ml, ush* __restrict__ P)
{
    long row = blockIdx.x;               // 0..16383
    float* sr = ml + row * 1024;
    int t = threadIdx.x;
    float s0 = sr[t], s1 = sr[t + 256];
    float m = fmaxf(s0, s1);
    m = wave_max(m);
    __shared__ float ra[4], rb[4];
    int w = t >> 6, l = t & 63;
    if (!l) ra[w] = m;
    __syncthreads();
    m = fmaxf(fmaxf(ra[0], ra[1]), fmaxf(ra[2], ra[3]));
    float p0 = __expf(s0 - m), p1 = __expf(s1 - m);
    ush h0 = f2bf_rne(p0), h1 = f2bf_rne(p1);
    P[row * 512 + t] = h0;
    P[row * 512 + t + 256] = h1;
    float ls = bf2f(h0) + bf2f(h1);      // sum what PV will actually use
    ls = wave_sum(ls);
    if (!l) rb[w] = ls;
    __syncthreads();
    if (t == 0) {
        sr[0] = m;
        sr[1] = rb[0] + rb[1] + rb[2] + rb[3];
    }
}

// ---------- final: out[:, 512:] /= l ----------
__global__ void normalize_kernel(float* __restrict__ o)
{
    long row = blockIdx.x;
    float inv = 1.0f / o[row * 1024 + 1];
    float* r = o + row * 1024 + 512;
    int t = threadIdx.x;
    r[t] *= inv; r[t + 256] *= inv;
}

// ---------- launch ----------
extern "C" void kernel_launch(void* const* d_in, const int* in_sizes, int n_in,
                              void* d_out, int out_size, void* d_ws, size_t ws_size,
                              hipStream_t stream)
{
    const float* sgm   = (const float*)d_in[0];
    const float* velo  = (const float*)d_in[1];
    const float* Wq    = (const float*)d_in[2];
    const float* bq    = (const float*)d_in[3];
    const float* gq    = (const float*)d_in[4];
    const float* betaq = (const float*)d_in[5];
    const float* Wk    = (const float*)d_in[6];
    const float* bk    = (const float*)d_in[7];
    const float* gk    = (const float*)d_in[8];
    const float* betak = (const float*)d_in[9];
    const float* Wv1   = (const float*)d_in[10];
    const float* bv1   = (const float*)d_in[11];
    const float* gv1   = (const float*)d_in[12];
    const float* betav1= (const float*)d_in[13];
    const float* Wv2   = (const float*)d_in[14];
    const float* bv2   = (const float*)d_in[15];
    const float* gv2   = (const float*)d_in[16];
    const float* betav2= (const float*)d_in[17];
    float* out = (float*)d_out;
    char*  wsb = (char*)d_ws;

    if (ws_size < 176 * MiB) return;   // proven >= 176 MiB in round 3

    // ws byte layout:
    // [0..64)    x hi/lo (velo, then sgm) -> then q hi/lo -> then x(sgm)
    // [64..128)  k hi/lo
    // [128..160) v1t hi/lo
    // [160..176) weight splits (12 MiB) -> P slab (16 MiB) -> Wv2 split
    ush* xh   = (ush*)wsb;
    ush* xl   = (ush*)(wsb + 32 * MiB);
    ush* kh   = (ush*)(wsb + 64 * MiB);
    ush* kl   = (ush*)(wsb + 96 * MiB);
    ush* v1th = (ush*)(wsb + 128 * MiB);
    ush* v1tl = (ush*)(wsb + 144 * MiB);
    ush* Wqh  = (ush*)(wsb + 160 * MiB);
    ush* Wql  = (ush*)(wsb + 162 * MiB);
    ush* Wkh  = (ush*)(wsb + 164 * MiB);
    ush* Wkl  = (ush*)(wsb + 166 * MiB);
    ush* Wv1h = (ush*)(wsb + 168 * MiB);
    ush* Wv1l = (ush*)(wsb + 169 * MiB);
    ush* P    = (ush*)(wsb + 160 * MiB);
    float* v1f = out + 8388608L;       // out bytes [32..64) MiB

    dim3 blk(256);

    // weight splits (Wv2 split later; its region becomes P during attention)
    split_kernel<<<1024, blk, 0, stream>>>(Wq,  Wqh,  Wql,  (long)CC_*DD);
    split_kernel<<<1024, blk, 0, stream>>>(Wk,  Wkh,  Wkl,  (long)CC_*DD);
    split_kernel<<<512,  blk, 0, stream>>>(Wv1, Wv1h, Wv1l, (long)HH*DD);

    // --- velo-derived: k, v1 ---
    split_kernel<<<16384, blk, 0, stream>>>(velo, xh, xl, (long)RR*DD);
    gemm3_kernel<1,0><<<dim3(8,128,1), blk, 0, stream>>>(
        xh, xl, Wkh, Wkl, out, nullptr, nullptr, DD, DD, DD, CC_, 0, 0, 0, 0);
    ln_relu_kernel<1024,true><<<RR, blk, 0, stream>>>(out, CC_, bk, gk, betak, nullptr, kh, kl, CC_);
    gemm3_kernel<1,0><<<dim3(4,128,1), blk, 0, stream>>>(
        xh, xl, Wv1h, Wv1l, out, nullptr, nullptr, DD, DD, DD, HH, 0, 0, 0, 0);
    ln_relu_kernel<512,false><<<RR, blk, 0, stream>>>(out, HH, bv1, gv1, betav1, v1f, nullptr, nullptr, HH);
    transpose_split_kernel<<<dim3(16,64,BB), blk, 0, stream>>>(v1f, v1th, v1tl);

    // --- sgm-derived: q (x region reused; q overwrites x after Yq) ---
    split_kernel<<<16384, blk, 0, stream>>>(sgm, xh, xl, (long)RR*DD);
    gemm3_kernel<1,0><<<dim3(8,128,1), blk, 0, stream>>>(
        xh, xl, Wqh, Wql, out, nullptr, nullptr, DD, DD, DD, CC_, 0, 0, 0, 0);
    ln_relu_kernel<1024,true><<<RR, blk, 0, stream>>>(out, CC_, bq, gq, betaq, nullptr, xh, xl, CC_);

    // --- attention ---
    // slab 0: raw S fp32 -> out[:, 0:512]; exp_pass derives m, P, l
    gemm3_kernel<1,0><<<dim3(4,16,8), blk, 0, stream>>>(
        xh, xl, kh, kl, out, nullptr, nullptr,
        CC_, CC_, CC_, 1024, 2048L*1024, 2048L*1024, 2048L*1024, 0);
    exp_pass_kernel<<<RR, blk, 0, stream>>>(out, P);
    gemm3_kernel<2,0><<<dim3(4,16,8), blk, 0, stream>>>(
        P, nullptr, v1th, v1tl, out + HH, nullptr, nullptr,
        512, 512, NN, CC_, 2048L*512, 512L*2048, 2048L*1024, 0);
    for (int s = 1; s < 4; ++s) {
        gemm3_kernel<1,1><<<dim3(4,16,8), blk, 0, stream>>>(
            xh, xl, kh + (long)s*512*1024, kl + (long)s*512*1024,
            nullptr, P, out, CC_, CC_, CC_, 0,
            2048L*1024, 2048L*1024, 0, 2048L*512);
        gemm3_kernel<2,2><<<dim3(4,16,8), blk, 0, stream>>>(
            P, nullptr, v1th + s*512, v1tl + s*512,
            out + HH, nullptr, nullptr, 512, 512, NN, CC_,
            2048L*512, 512L*2048, 2048L*1024, 0);
    }
    normalize_kernel<<<RR, blk, 0, stream>>>(out);

    // --- v2 last (out[:, :512] free now; q and P regions dead) ---
    split_kernel<<<16384, blk, 0, stream>>>(sgm, xh, xl, (long)RR*DD);
    ush* Wv2h = (ush*)(wsb + 160 * MiB);
    ush* Wv2l = (ush*)(wsb + 161 * MiB);
    split_kernel<<<512, blk, 0, stream>>>(Wv2, Wv2h, Wv2l, (long)HH*DD);
    gemm3_kernel<1,0><<<dim3(4,128,1), blk, 0, stream>>>(
        xh, xl, Wv2h, Wv2l, out, nullptr, nullptr, DD, DD, DD, CC_, 0, 0, 0, 0);
    ln_relu_kernel<512,false><<<RR, blk, 0, stream>>>(out, CC_, bv2, gv2, betav2, out, nullptr, nullptr, CC_);
}

// Round 6
// 938.341 us; speedup vs baseline: 1.5933x; 1.4110x over previous
//
#include <hip/hip_runtime.h>
#include <hip/hip_bf16.h>

// B=8, N=2048, D=1024, C=1024, H=512 (fp32 in/out)
//  q = LNReLU(sgm@Wq^T+bq); k = LNReLU(velo@Wk^T+bk)
//  S = q k^T; P = softmax(S); v1 = LNReLU(velo@Wv1^T); v2 = LNReLU(sgm@Wv2^T)
//  out = concat(v2, P@v1)
//
// Round 6: round-5 counters showed big GEMMs at 50% HBM / FETCH 600 MB
// (ideal ~70 MB): cross-XCD A-panel duplication — the 8 blocks sharing an
// A-panel round-robin onto 8 different XCD L2s. Fix: bijective XCD swizzle
// of the flattened block id inside gemm3 (each XCD owns contiguous panels).
// Everything else identical to round 5 (absmax 0.03125).

#define BB 8
#define NN 2048
#define DD 1024
#define CC_ 1024
#define HH 512
#define RR (BB*NN)   // 16384 rows

typedef unsigned short ush;
typedef short bf16x8 __attribute__((ext_vector_type(8)));
typedef float f32x4  __attribute__((ext_vector_type(4)));

#define MiB (1024L*1024L)

// ---------- helpers ----------
__device__ __forceinline__ ush f2bf_rne(float x) {
    unsigned u = __float_as_uint(x);
    return (ush)((u + 0x7fffu + ((u >> 16) & 1u)) >> 16);
}
__device__ __forceinline__ float bf2f(ush h) {
    return __uint_as_float((unsigned)h << 16);
}
__device__ __forceinline__ float wave_sum(float v) {
    #pragma unroll
    for (int o = 32; o; o >>= 1) v += __shfl_down(v, o);
    return v;
}
__device__ __forceinline__ float wave_max(float v) {
    #pragma unroll
    for (int o = 32; o; o >>= 1) v = fmaxf(v, __shfl_down(v, o));
    return v;
}

// LDS tile [128 rows][32 bf16] = 64 B/row. Swizzle XORs byte bits 4..5 with
// (row>>1)&3 (involution; preserves 16B chunks).
__device__ __forceinline__ int swzb(int row, int kbyte) {
    return ((row << 6) | kbyte) ^ (((row >> 1) & 3) << 4);
}

// async global->LDS, 16B/lane. LDS dest wave-uniform base + lane*16;
// global src per-lane (pre-swizzled so linear LDS holds swizzled layout).
__device__ __forceinline__ void glds16(const void* g, void* l) {
    __builtin_amdgcn_global_load_lds(
        (const __attribute__((address_space(1))) unsigned*)g,
        (__attribute__((address_space(3))) unsigned*)l, 16, 0, 0);
}

// ---------- split-bf16 MFMA GEMM ----------
// C[M,N] = A[M,K] @ B[N,K]^T. Tile 128x128, BK=32, 4 waves -> 64x64 each.
// AM=1: A pre-split hi/lo, 3 passes (ah*bh, ah*bl, al*bh).
// AM=2: A single bf16,    2 passes (a*bh, a*bl).        B always hi/lo.
// EPI=0: store C fp32. EPI=1: p=exp(s-m), store P bf16 + atomicAdd l.
// EPI=2: C += acc.
template<int AM, int EPI>
__global__ __launch_bounds__(256, 4)
void gemm3_kernel(const ush* __restrict__ A0, const ush* __restrict__ A1,
                  const ush* __restrict__ B0, const ush* __restrict__ B1,
                  float* __restrict__ C, ush* __restrict__ Pout,
                  float* __restrict__ ml,
                  int K, int lda, int ldb, int ldc,
                  long sAz, long sBz, long sCz, long sPz)
{
    __shared__ alignas(16) ush aHi[128*32];
    __shared__ alignas(16) ush aLo[128*32];
    __shared__ alignas(16) ush bHi[128*32];
    __shared__ alignas(16) ush bLo[128*32];

    // XCD-aware bijective swizzle (all grids here are multiples of 8):
    // consecutive work (x fastest, then y, then z) lands contiguously on one
    // XCD so blocks sharing an A-panel hit the same L2.
    long wg  = (long)blockIdx.x +
               (long)gridDim.x * ((long)blockIdx.y + (long)gridDim.y * blockIdx.z);
    long nwg = (long)gridDim.x * gridDim.y * gridDim.z;
    long swz = (wg & 7) * (nwg >> 3) + (wg >> 3);
    const int bx = (int)(swz % gridDim.x);
    long rem = swz / gridDim.x;
    const int by = (int)(rem % gridDim.y);
    const long bz = rem / gridDim.y;

    const long mbase = (long)by << 7;
    const long nbase = (long)bx << 7;
    const int  t    = threadIdx.x;
    const int  wave = t >> 6, lane = t & 63;
    const int  wr = (wave >> 1) << 6;
    const int  wc = (wave & 1)  << 6;
    const int  fr = lane & 15;
    const int  kg = lane >> 4;

    const ush* Ah = A0 + bz * sAz;
    const ush* Bh = B0 + bz * sBz;
    const ush* Bl = B1 + bz * sBz;

    f32x4 acc[4][4] = {};

    for (int k0 = 0; k0 < K; k0 += 32) {
        #pragma unroll
        for (int i = 0; i < 2; ++i) {
            int rl = (wave << 5) + (i << 4) + (lane >> 2);
            int cs = ((lane & 3) ^ ((rl >> 1) & 3)) << 3;
            long goA = (mbase + rl) * (long)lda + k0 + cs;
            long goB = (nbase + rl) * (long)ldb + k0 + cs;
            glds16(Ah + goA, &aHi[(wave << 10) + (i << 9)]);
            if constexpr (AM == 1) {
                const ush* Al_ = A1 + bz * sAz;
                glds16(Al_ + goA, &aLo[(wave << 10) + (i << 9)]);
            }
            glds16(Bh + goB, &bHi[(wave << 10) + (i << 9)]);
            glds16(Bl + goB, &bLo[(wave << 10) + (i << 9)]);
        }
        __syncthreads();

        bf16x8 ah[4], al[4], bh[4], bl[4];
        #pragma unroll
        for (int i = 0; i < 4; ++i) {
            int ra = wr + (i << 4) + fr, rb = wc + (i << 4) + fr;
            ah[i] = *(const bf16x8*)(aHi + (swzb(ra, kg << 4) >> 1));
            if constexpr (AM == 1)
                al[i] = *(const bf16x8*)(aLo + (swzb(ra, kg << 4) >> 1));
            bh[i] = *(const bf16x8*)(bHi + (swzb(rb, kg << 4) >> 1));
            bl[i] = *(const bf16x8*)(bLo + (swzb(rb, kg << 4) >> 1));
        }
        #pragma unroll
        for (int i = 0; i < 4; ++i) {
            #pragma unroll
            for (int j = 0; j < 4; ++j) {
                acc[i][j] = __builtin_amdgcn_mfma_f32_16x16x32_bf16(ah[i], bh[j], acc[i][j], 0, 0, 0);
                acc[i][j] = __builtin_amdgcn_mfma_f32_16x16x32_bf16(ah[i], bl[j], acc[i][j], 0, 0, 0);
                if constexpr (AM == 1)
                    acc[i][j] = __builtin_amdgcn_mfma_f32_16x16x32_bf16(al[i], bh[j], acc[i][j], 0, 0, 0);
            }
        }
        __syncthreads();
    }

    // C/D layout (m89): col = lane&15, row = (lane>>4)*4 + reg
    if constexpr (EPI == 1) {
        ush*   Pb  = Pout + bz * sPz;
        float* mlb = ml + bz * 2048L * 1024;
        #pragma unroll
        for (int i = 0; i < 4; ++i) {
            #pragma unroll
            for (int q = 0; q < 4; ++q) {
                long grow = mbase + wr + (i << 4) + (kg << 2) + q;   // row in batch
                float m = mlb[grow * 1024];
                float rs = 0.f;
                #pragma unroll
                for (int j = 0; j < 4; ++j) {
                    float p = __expf(acc[i][j][q] - m);
                    rs += p;
                    Pb[grow * 512 + nbase + wc + (j << 4) + fr] = f2bf_rne(p);
                }
                rs += __shfl_xor(rs, 1); rs += __shfl_xor(rs, 2);
                rs += __shfl_xor(rs, 4); rs += __shfl_xor(rs, 8);
                if (fr == 0) atomicAdd(&mlb[grow * 1024 + 1], rs);
            }
        }
    } else {
        float* Cb = C + bz * sCz;
        #pragma unroll
        for (int i = 0; i < 4; ++i) {
            #pragma unroll
            for (int q = 0; q < 4; ++q) {
                long grow = mbase + wr + (i << 4) + (kg << 2) + q;
                float* crow = Cb + grow * (long)ldc + nbase + wc + fr;
                #pragma unroll
                for (int j = 0; j < 4; ++j) {
                    if constexpr (EPI == 2) crow[j << 4] = crow[j << 4] + acc[i][j][q];
                    else                    crow[j << 4] = acc[i][j][q];
                }
            }
        }
    }
}

// ---------- bias + LayerNorm + ReLU; optional hi/lo bf16 output ----------
template<int NC, bool HILO>
__global__ void ln_relu_kernel(const float* __restrict__ Y, int ldy,
                               const float* __restrict__ bias,
                               const float* __restrict__ g, const float* __restrict__ beta,
                               float* __restrict__ outf, ush* __restrict__ oh,
                               ush* __restrict__ ol, int ldo)
{
    constexpr int PER = NC / 256;
    long row = blockIdx.x;
    const float* yr = Y + row * (long)ldy;
    int t = threadIdx.x;
    float v[PER]; float s = 0.f, s2 = 0.f;
    #pragma unroll
    for (int i = 0; i < PER; ++i) {
        int c = t + (i << 8);
        float x = yr[c] + bias[c];
        v[i] = x; s += x; s2 += x * x;
    }
    s = wave_sum(s); s2 = wave_sum(s2);
    __shared__ float ra[4], rb[4];
    int w = t >> 6, l = t & 63;
    if (!l) { ra[w] = s; rb[w] = s2; }
    __syncthreads();
    s  = ra[0] + ra[1] + ra[2] + ra[3];
    s2 = rb[0] + rb[1] + rb[2] + rb[3];
    float mu  = s * (1.0f / NC);
    float var = s2 * (1.0f / NC) - mu * mu;
    float inv = rsqrtf(var + 1e-5f);
    #pragma unroll
    for (int i = 0; i < PER; ++i) {
        int c = t + (i << 8);
        float x = (v[i] - mu) * inv * g[c] + beta[c];
        x = fmaxf(x, 0.0f);
        if constexpr (HILO) {
            ush h = f2bf_rne(x);
            ush lo = f2bf_rne(x - __uint_as_float((unsigned)h << 16));
            oh[row * (long)ldo + c] = h;
            ol[row * (long)ldo + c] = lo;
        } else {
            outf[row * (long)ldo + c] = x;
        }
    }
}

// ---------- fp32 -> hi/lo bf16 split (flat) ----------
__global__ void split_kernel(const float* __restrict__ in, ush* __restrict__ h,
                             ush* __restrict__ l, long n)
{
    long i = ((long)blockIdx.x * 256 + threadIdx.x) * 4;
    if (i >= n) return;
    float4 v = *(const float4*)(in + i);
    ushort4 hh, ll;
    hh.x = f2bf_rne(v.x); ll.x = f2bf_rne(v.x - __uint_as_float((unsigned)hh.x << 16));
    hh.y = f2bf_rne(v.y); ll.y = f2bf_rne(v.y - __uint_as_float((unsigned)hh.y << 16));
    hh.z = f2bf_rne(v.z); ll.z = f2bf_rne(v.z - __uint_as_float((unsigned)hh.z << 16));
    hh.w = f2bf_rne(v.w); ll.w = f2bf_rne(v.w - __uint_as_float((unsigned)hh.w << 16));
    *(ushort4*)(h + i) = hh;
    *(ushort4*)(l + i) = ll;
}

// ---------- per-batch transpose [2048,512] -> [512,2048], hi/lo split ----------
__global__ void transpose_split_kernel(const float* __restrict__ in,
                                       ush* __restrict__ oh, ush* __restrict__ ol)
{
    __shared__ float tile[32][33];
    long bz = blockIdx.z;
    const float* I = in + bz * (long)NN * HH;
    ush* OH = oh + bz * (long)HH * NN;
    ush* OL = ol + bz * (long)HH * NN;
    int c0 = blockIdx.x << 5, r0 = blockIdx.y << 5;
    int tx = threadIdx.x & 31, ty = threadIdx.x >> 5;   // 32 x 8
    #pragma unroll
    for (int i = 0; i < 32; i += 8)
        tile[ty + i][tx] = I[(long)(r0 + ty + i) * HH + c0 + tx];
    __syncthreads();
    #pragma unroll
    for (int i = 0; i < 32; i += 8) {
        float x = tile[tx][ty + i];
        ush h = f2bf_rne(x);
        ush lo = f2bf_rne(x - __uint_as_float((unsigned)h << 16));
        long o = (long)(c0 + ty + i) * NN + r0 + tx;
        OH[o] = h; OL[o] = lo;
    }
}

// ---------- exp pass over slab-0 scores ----------
// S fp32 at ml[row*1024 + 0..511]; computes m=rowmax, P=exp(S-m) bf16,
// l=rowsum; stores m,l at ml[row*1024 + 0/1] (after S consumed).
__global__ void exp_pass_kernel(float* __restrict__ ml, ush* __restrict__ P)
{
    long row = blockIdx.x;               // 0..16383
    float* sr = ml + row * 1024;
    int t = threadIdx.x;
    float s0 = sr[t], s1 = sr[t + 256];
    float m = fmaxf(s0, s1);
    m = wave_max(m);
    __shared__ float ra[4], rb[4];
    int w = t >> 6, l = t & 63;
    if (!l) ra[w] = m;
    __syncthreads();
    m = fmaxf(fmaxf(ra[0], ra[1]), fmaxf(ra[2], ra[3]));
    float p0 = __expf(s0 - m), p1 = __expf(s1 - m);
    ush h0 = f2bf_rne(p0), h1 = f2bf_rne(p1);
    P[row * 512 + t] = h0;
    P[row * 512 + t + 256] = h1;
    float ls = bf2f(h0) + bf2f(h1);      // sum what PV will actually use
    ls = wave_sum(ls);
    if (!l) rb[w] = ls;
    __syncthreads();
    if (t == 0) {
        sr[0] = m;
        sr[1] = rb[0] + rb[1] + rb[2] + rb[3];
    }
}

// ---------- final: out[:, 512:] /= l ----------
__global__ void normalize_kernel(float* __restrict__ o)
{
    long row = blockIdx.x;
    float inv = 1.0f / o[row * 1024 + 1];
    float* r = o + row * 1024 + 512;
    int t = threadIdx.x;
    r[t] *= inv; r[t + 256] *= inv;
}

// ---------- launch ----------
extern "C" void kernel_launch(void* const* d_in, const int* in_sizes, int n_in,
                              void* d_out, int out_size, void* d_ws, size_t ws_size,
                              hipStream_t stream)
{
    const float* sgm   = (const float*)d_in[0];
    const float* velo  = (const float*)d_in[1];
    const float* Wq    = (const float*)d_in[2];
    const float* bq    = (const float*)d_in[3];
    const float* gq    = (const float*)d_in[4];
    const float* betaq = (const float*)d_in[5];
    const float* Wk    = (const float*)d_in[6];
    const float* bk    = (const float*)d_in[7];
    const float* gk    = (const float*)d_in[8];
    const float* betak = (const float*)d_in[9];
    const float* Wv1   = (const float*)d_in[10];
    const float* bv1   = (const float*)d_in[11];
    const float* gv1   = (const float*)d_in[12];
    const float* betav1= (const float*)d_in[13];
    const float* Wv2   = (const float*)d_in[14];
    const float* bv2   = (const float*)d_in[15];
    const float* gv2   = (const float*)d_in[16];
    const float* betav2= (const float*)d_in[17];
    float* out = (float*)d_out;
    char*  wsb = (char*)d_ws;

    if (ws_size < 176 * MiB) return;   // proven >= 176 MiB in round 3

    // ws byte layout:
    // [0..64)    x hi/lo (velo, then sgm) -> then q hi/lo -> then x(sgm)
    // [64..128)  k hi/lo
    // [128..160) v1t hi/lo
    // [160..176) weight splits (12 MiB) -> P slab (16 MiB) -> Wv2 split
    ush* xh   = (ush*)wsb;
    ush* xl   = (ush*)(wsb + 32 * MiB);
    ush* kh   = (ush*)(wsb + 64 * MiB);
    ush* kl   = (ush*)(wsb + 96 * MiB);
    ush* v1th = (ush*)(wsb + 128 * MiB);
    ush* v1tl = (ush*)(wsb + 144 * MiB);
    ush* Wqh  = (ush*)(wsb + 160 * MiB);
    ush* Wql  = (ush*)(wsb + 162 * MiB);
    ush* Wkh  = (ush*)(wsb + 164 * MiB);
    ush* Wkl  = (ush*)(wsb + 166 * MiB);
    ush* Wv1h = (ush*)(wsb + 168 * MiB);
    ush* Wv1l = (ush*)(wsb + 169 * MiB);
    ush* P    = (ush*)(wsb + 160 * MiB);
    float* v1f = out + 8388608L;       // out bytes [32..64) MiB

    dim3 blk(256);

    // weight splits (Wv2 split later; its region becomes P during attention)
    split_kernel<<<1024, blk, 0, stream>>>(Wq,  Wqh,  Wql,  (long)CC_*DD);
    split_kernel<<<1024, blk, 0, stream>>>(Wk,  Wkh,  Wkl,  (long)CC_*DD);
    split_kernel<<<512,  blk, 0, stream>>>(Wv1, Wv1h, Wv1l, (long)HH*DD);

    // --- velo-derived: k, v1 ---
    split_kernel<<<16384, blk, 0, stream>>>(velo, xh, xl, (long)RR*DD);
    gemm3_kernel<1,0><<<dim3(8,128,1), blk, 0, stream>>>(
        xh, xl, Wkh, Wkl, out, nullptr, nullptr, DD, DD, DD, CC_, 0, 0, 0, 0);
    ln_relu_kernel<1024,true><<<RR, blk, 0, stream>>>(out, CC_, bk, gk, betak, nullptr, kh, kl, CC_);
    gemm3_kernel<1,0><<<dim3(4,128,1), blk, 0, stream>>>(
        xh, xl, Wv1h, Wv1l, out, nullptr, nullptr, DD, DD, DD, HH, 0, 0, 0, 0);
    ln_relu_kernel<512,false><<<RR, blk, 0, stream>>>(out, HH, bv1, gv1, betav1, v1f, nullptr, nullptr, HH);
    transpose_split_kernel<<<dim3(16,64,BB), blk, 0, stream>>>(v1f, v1th, v1tl);

    // --- sgm-derived: q (x region reused; q overwrites x after Yq) ---
    split_kernel<<<16384, blk, 0, stream>>>(sgm, xh, xl, (long)RR*DD);
    gemm3_kernel<1,0><<<dim3(8,128,1), blk, 0, stream>>>(
        xh, xl, Wqh, Wql, out, nullptr, nullptr, DD, DD, DD, CC_, 0, 0, 0, 0);
    ln_relu_kernel<1024,true><<<RR, blk, 0, stream>>>(out, CC_, bq, gq, betaq, nullptr, xh, xl, CC_);

    // --- attention ---
    // slab 0: raw S fp32 -> out[:, 0:512]; exp_pass derives m, P, l
    gemm3_kernel<1,0><<<dim3(4,16,8), blk, 0, stream>>>(
        xh, xl, kh, kl, out, nullptr, nullptr,
        CC_, CC_, CC_, 1024, 2048L*1024, 2048L*1024, 2048L*1024, 0);
    exp_pass_kernel<<<RR, blk, 0, stream>>>(out, P);
    gemm3_kernel<2,0><<<dim3(4,16,8), blk, 0, stream>>>(
        P, nullptr, v1th, v1tl, out + HH, nullptr, nullptr,
        512, 512, NN, CC_, 2048L*512, 512L*2048, 2048L*1024, 0);
    for (int s = 1; s < 4; ++s) {
        gemm3_kernel<1,1><<<dim3(4,16,8), blk, 0, stream>>>(
            xh, xl, kh + (long)s*512*1024, kl + (long)s*512*1024,
            nullptr, P, out, CC_, CC_, CC_, 0,
            2048L*1024, 2048L*1024, 0, 2048L*512);
        gemm3_kernel<2,2><<<dim3(4,16,8), blk, 0, stream>>>(
            P, nullptr, v1th + s*512, v1tl + s*512,
            out + HH, nullptr, nullptr, 512, 512, NN, CC_,
            2048L*512, 512L*2048, 2048L*1024, 0);
    }
    normalize_kernel<<<RR, blk, 0, stream>>>(out);

    // --- v2 last (out[:, :512] free now; q and P regions dead) ---
    split_kernel<<<16384, blk, 0, stream>>>(sgm, xh, xl, (long)RR*DD);
    ush* Wv2h = (ush*)(wsb + 160 * MiB);
    ush* Wv2l = (ush*)(wsb + 161 * MiB);
    split_kernel<<<512, blk, 0, stream>>>(Wv2, Wv2h, Wv2l, (long)HH*DD);
    gemm3_kernel<1,0><<<dim3(4,128,1), blk, 0, stream>>>(
        xh, xl, Wv2h, Wv2l, out, nullptr, nullptr, DD, DD, DD, CC_, 0, 0, 0, 0);
    ln_relu_kernel<512,false><<<RR, blk, 0, stream>>>(out, CC_, bv2, gv2, betav2, out, nullptr, nullptr, CC_);
}